// Round 7
// baseline (3873.680 us; speedup 1.0000x reference)
//
#include <hip/hip_runtime.h>
#include <hip/hip_bf16.h>
#include <math.h>

// Problem constants (from reference)
#define BB 64
#define TT 2048
#define VV 4096
#define EE 128
#define H2 128
#define SS 8
#define CC 2

typedef _Float16 h2f __attribute__((ext_vector_type(2)));

__device__ __forceinline__ float sigf(float x) { return 1.f / (1.f + __expf(-x)); }
__device__ __forceinline__ float tanh_fast(float x) { return 1.f - 2.f / (__expf(2.f * x) + 1.f); }

__device__ __forceinline__ float dot2acc(h2f w, h2f h, float acc) {
#if __has_builtin(__builtin_amdgcn_fdot2)
    return __builtin_amdgcn_fdot2(w, h, acc, false);
#else
    return fmaf((float)w.x, (float)h.x, fmaf((float)w.y, (float)h.y, acc));
#endif
}

// Workgroup barrier with LDS-only drain (no vmcnt(0) — global prefetch loads
// stay in flight across steps).
__device__ __forceinline__ void lds_barrier() {
    asm volatile("s_waitcnt lgkmcnt(0)\n\ts_barrier" ::: "memory");
}

// ---------------------------------------------------------------------------
// Kernel 1: EG gate-bias table, packed f16 PAIR layout:
//   EGh[v][d][p] = half2{ gate rA(p), gate rB(p) },  p in [0,256)
//   p<128: rA=p (i_u), rB=128+p (f_u);  p>=128: rA=128+p (g_u), rB=256+p (o_u)
// ---------------------------------------------------------------------------
__global__ __launch_bounds__(256) void eg_gemm(
    const float* __restrict__ emb,
    const float* __restrict__ Wf, const float* __restrict__ bf,
    const float* __restrict__ Wb, const float* __restrict__ bb,
    _Float16* __restrict__ EGh)
{
    __shared__ float As[64][68];
    __shared__ float Bs[64][68];

    const int tid = threadIdx.x;
    const int tx = tid & 15, ty = tid >> 4;
    const int m0 = blockIdx.y * 64;
    const int n0 = blockIdx.x * 64;

    const float* Bsrc;
    const float* bias;
    if (n0 < 512) { Bsrc = Wf + n0 * EE; bias = bf + n0; }
    else          { Bsrc = Wb + (n0 - 512) * EE; bias = bb + (n0 - 512); }

    float acc[4][4] = {};

    for (int kc = 0; kc < 2; ++kc) {
        for (int c = tid; c < 1024; c += 256) {
            int r = c >> 4, q = c & 15;
            float4 av = *(const float4*)(emb + (size_t)(m0 + r) * EE + kc * 64 + q * 4);
            As[q * 4 + 0][r] = av.x; As[q * 4 + 1][r] = av.y;
            As[q * 4 + 2][r] = av.z; As[q * 4 + 3][r] = av.w;
            float4 bv = *(const float4*)(Bsrc + (size_t)r * EE + kc * 64 + q * 4);
            Bs[q * 4 + 0][r] = bv.x; Bs[q * 4 + 1][r] = bv.y;
            Bs[q * 4 + 2][r] = bv.z; Bs[q * 4 + 3][r] = bv.w;
        }
        __syncthreads();
        #pragma unroll 8
        for (int k = 0; k < 64; ++k) {
            float4 a4 = *(const float4*)&As[k][4 * ty];
            float4 b4 = *(const float4*)&Bs[k][4 * tx];
            float a[4] = {a4.x, a4.y, a4.z, a4.w};
            float b[4] = {b4.x, b4.y, b4.z, b4.w};
            #pragma unroll
            for (int i = 0; i < 4; ++i)
                #pragma unroll
                for (int jn = 0; jn < 4; ++jn)
                    acc[i][jn] = fmaf(a[i], b[jn], acc[i][jn]);
        }
        __syncthreads();
    }

    #pragma unroll
    for (int i = 0; i < 4; ++i) {
        int m = m0 + 4 * ty + i;                 // vocab index v
        #pragma unroll
        for (int jn = 0; jn < 4; ++jn) {
            int nn = 4 * tx + jn;
            int n = n0 + nn;                     // combined gate col
            int d = n >> 9;
            int r = n & 511;
            int slot = (r >> 7) & 1;
            int p = (r & 127) + (r >= 256 ? 128 : 0);
            EGh[(((size_t)m * 2 + d) * 256 + p) * 2 + slot] =
                (_Float16)(acc[i][jn] + bias[nn]);
        }
    }
}

// ---------------------------------------------------------------------------
// Kernel 2: fused LSTM recurrence + ragged segment max-pool, TWO batch
// streams per block sharing the weight registers.
// grid = 64 blocks: pair = bid>>1 (batch elements 2*pair, 2*pair+1), dir = bid&1.
// seq_lengths is sorted descending, so paired lengths are near-equal.
// 256 threads = 4 waves, 1 wave/SIMD. Wave wg, lane l: unit u = wg*32+(l>>1).
//   even lane: W_hh rows (i_u,f_u) + cell state; odd: (g_u,o_u).
// Per step: 128 readlane + 256 fdot2 (both streams, 4 indep acc chains) —
// two recurrence steps per iteration, issue-bound (fills the 1-wave/SIMD
// latency bubbles that capped rounds 4-5). Streams past their own L are
// predicated (carry/pool frozen = reference's masked-step semantics).
// ---------------------------------------------------------------------------
__global__ __launch_bounds__(256, 1) void lstm_rec(
    const int* __restrict__ sentence, const int* __restrict__ lens,
    const float* __restrict__ Whhf, const float* __restrict__ Whhb,
    const _Float16* __restrict__ EGh, float* __restrict__ pws)
{
    const int pair = blockIdx.x >> 1;
    const int dir = blockIdx.x & 1;     // 0 = forward, 1 = backward
    const int b0 = 2 * pair, b1 = 2 * pair + 1;
    const int tid = threadIdx.x;
    const int l = tid & 63;             // lane in wave
    const int wg = tid >> 6;            // wave 0..3
    const int u = wg * 32 + (l >> 1);   // hidden unit this lane pair covers
    const bool evn = (l & 1) == 0;      // even lane: (i,f) + cell state
    const int L0 = lens[b0];
    const int L1 = lens[b1];
    const int Lmax = max(L0, L1);
    const int* __restrict__ srow0 = sentence + (size_t)b0 * TT;
    const int* __restrict__ srow1 = sentence + (size_t)b1 * TT;

    const int r0 = evn ? u : (256 + u);
    const int r1 = r0 + 128;
    const float* __restrict__ Wh = (dir == 0 ? Whhf : Whhb);

    // --- W_hh rows -> packed f16 pairs: 128 arch VGPRs, shared by streams ---
    h2f w0[64], w1[64];
    #pragma unroll
    for (int k4 = 0; k4 < 32; ++k4) {
        float4 a = *(const float4*)(Wh + (size_t)r0 * H2 + 4 * k4);
        w0[2 * k4 + 0].x = (_Float16)a.x; w0[2 * k4 + 0].y = (_Float16)a.y;
        w0[2 * k4 + 1].x = (_Float16)a.z; w0[2 * k4 + 1].y = (_Float16)a.w;
        float4 bq = *(const float4*)(Wh + (size_t)r1 * H2 + 4 * k4);
        w1[2 * k4 + 0].x = (_Float16)bq.x; w1[2 * k4 + 0].y = (_Float16)bq.y;
        w1[2 * k4 + 1].x = (_Float16)bq.z; w1[2 * k4 + 1].y = (_Float16)bq.w;
    }

    __shared__ int hpk[2][2][64];       // [stream][buf] packed f16 h pairs
    if (tid < 128) hpk[tid >> 6][0][tid & 63] = 0;

    // per-lane EG pair element (as packed dword); index for token v: v*512
    const int p = evn ? u : (128 + u);
    const unsigned* __restrict__ egp = (const unsigned*)EGh + dir * 256 + p;

    float c0 = 0.f, c1 = 0.f;
    float pm0 = -INFINITY, pm1 = -INFINITY;

    // per-stream pooling state (wave-uniform -> SGPRs)
    const int wseg0 = (L0 + SS - 1) >> 3;
    const int wseg1 = (L1 + SS - 1) >> 3;
    const bool haspad0 = (SS * wseg0 > L0), haspad1 = (SS * wseg1 > L1);
    const int padlo0 = L0 / wseg0, padlo1 = L1 / wseg1;
    int cur0 = dir ? (SS - 1) : 0, cur1 = dir ? (SS - 1) : 0;
    int nb0 = dir ? (SS - 1) * wseg0 : wseg0;
    int nb1 = dir ? (SS - 1) * wseg1 : wseg1;

    // --- prefetch FIFO depth 3 per stream ---
    #define CLIDX(Lk, t) (dir ? min(TT - 1, max(0, (Lk) - 1 - (t))) : min(TT - 1, (t)))
    unsigned xfa0 = egp[(size_t)srow0[CLIDX(L0, 0)] * 512];
    unsigned xfa1 = egp[(size_t)srow0[CLIDX(L0, 1)] * 512];
    unsigned xfa2 = egp[(size_t)srow0[CLIDX(L0, 2)] * 512];
    int toka3 = srow0[CLIDX(L0, 3)];
    unsigned xfb0 = egp[(size_t)srow1[CLIDX(L1, 0)] * 512];
    unsigned xfb1 = egp[(size_t)srow1[CLIDX(L1, 1)] * 512];
    unsigned xfb2 = egp[(size_t)srow1[CLIDX(L1, 2)] * 512];
    int tokb3 = srow1[CLIDX(L1, 3)];

    __syncthreads();                    // hpk init visible (one-time drain)

    for (int t = 0; t < Lmax; ++t) {
        const int buf = t & 1;
        // ---- h for this step (both streams) ----
        int hp0 = hpk[0][buf][l];
        int hp1 = hpk[1][buf][l];

        // ---- issue EG gathers for step t+3 ----
        unsigned pfa = egp[(size_t)toka3 * 512];
        unsigned pfb = egp[(size_t)tokb3 * 512];
        toka3 = srow0[CLIDX(L0, t + 4)];
        tokb3 = srow1[CLIDX(L1, t + 4)];

        // ---- dot: 128 readlane + 256 fdot2, 4 independent chains ----
        float a00 = 0.f, a01 = 0.f, a10 = 0.f, a11 = 0.f;
        #pragma unroll
        for (int k = 0; k < 64; ++k) {
            int hk0 = __builtin_amdgcn_readlane(hp0, k);
            int hk1 = __builtin_amdgcn_readlane(hp1, k);
            h2f hv0 = __builtin_bit_cast(h2f, hk0);
            h2f hv1 = __builtin_bit_cast(h2f, hk1);
            a00 = dot2acc(w0[k], hv0, a00);
            a01 = dot2acc(w1[k], hv0, a01);
            a10 = dot2acc(w0[k], hv1, a10);
            a11 = dot2acc(w1[k], hv1, a11);
        }
        h2f xva = __builtin_bit_cast(h2f, xfa0);
        h2f xvb = __builtin_bit_cast(h2f, xfb0);
        float g00 = a00 + (float)xva.x, g01 = a01 + (float)xva.y;
        float g10 = a10 + (float)xvb.x, g11 = a11 + (float)xvb.y;

        // ---- stream 0 tail ----
        float s0o = sigf(g01);
        float t0o = evn ? sigf(g00) : tanh_fast(g00);
        // ---- stream 1 tail ----
        float s1o = sigf(g11);
        float t1o = evn ? sigf(g10) : tanh_fast(g10);

        float t0x = __shfl_xor(t0o, 1, 64);
        float s0x = __shfl_xor(s0o, 1, 64);
        float t1x = __shfl_xor(t1o, 1, 64);
        float s1x = __shfl_xor(s1o, 1, 64);

        c0 = s0o * c0 + t0o * t0x;
        float hn0 = s0x * tanh_fast(c0);
        c1 = s1o * c1 + t1o * t1x;
        float hn1 = s1x * tanh_fast(c1);

        // ---- pooling (uniform branches; stream frozen past its own L) ----
        if (t < L0) {
            const int tt = dir ? (L0 - 1 - t) : t;
            bool bnd = dir ? (tt < nb0) : (tt >= nb0);
            if (bnd) {
                if (evn) {
                    float v = pm0;
                    if (haspad0 && cur0 >= padlo0) v = fmaxf(v, 0.f);
                    pws[(((size_t)b0 * 2 + dir) * SS + cur0) * H2 + u] = v;
                }
                pm0 = -INFINITY;
                cur0 += dir ? -1 : 1;
                nb0 += dir ? -wseg0 : wseg0;
            }
            pm0 = fmaxf(pm0, hn0);
        }
        if (t < L1) {
            const int tt = dir ? (L1 - 1 - t) : t;
            bool bnd = dir ? (tt < nb1) : (tt >= nb1);
            if (bnd) {
                if (evn) {
                    float v = pm1;
                    if (haspad1 && cur1 >= padlo1) v = fmaxf(v, 0.f);
                    pws[(((size_t)b1 * 2 + dir) * SS + cur1) * H2 + u] = v;
                }
                pm1 = -INFINITY;
                cur1 += dir ? -1 : 1;
                nb1 += dir ? -wseg1 : wseg1;
            }
            pm1 = fmaxf(pm1, hn1);
        }

        // ---- publish h (f16) into the other buffer; LDS-only barrier ----
        if (evn) {
            ((_Float16*)hpk[0][buf ^ 1])[u] = (_Float16)hn0;
            ((_Float16*)hpk[1][buf ^ 1])[u] = (_Float16)hn1;
        }
        lds_barrier();

        // rotate prefetch FIFOs
        xfa0 = xfa1; xfa1 = xfa2; xfa2 = pfa;
        xfb0 = xfb1; xfb1 = xfb2; xfb2 = pfb;
    }
    #undef CLIDX

    if (evn) {
        float v = pm0;
        if (haspad0 && cur0 >= padlo0) v = fmaxf(v, 0.f);
        pws[(((size_t)b0 * 2 + dir) * SS + cur0) * H2 + u] = v;
        float v1 = pm1;
        if (haspad1 && cur1 >= padlo1) v1 = fmaxf(v1, 0.f);
        pws[(((size_t)b1 * 2 + dir) * SS + cur1) * H2 + u] = v1;
    }
}

// ---------------------------------------------------------------------------
// Kernel 3: out[b,c] = b_dense[c] + sum_k flat[b,k] * W_dense[c,k]
// ---------------------------------------------------------------------------
__global__ __launch_bounds__(256) void dense_k(
    const float* __restrict__ pws, const float* __restrict__ Wd,
    const float* __restrict__ bd, float* __restrict__ out)
{
    const int b = blockIdx.x;
    const int tid = threadIdx.x;
    float a0 = 0.f, a1 = 0.f;
    for (int k = tid; k < 2048; k += 256) {
        int h = k >> 3, s = k & 7;
        int dir = h >> 7, j = h & 127;
        float v = pws[(((size_t)b * 2 + dir) * SS + s) * H2 + j];
        a0 = fmaf(v, Wd[k], a0);
        a1 = fmaf(v, Wd[2048 + k], a1);
    }
    __shared__ float r0[256], r1[256];
    r0[tid] = a0; r1[tid] = a1;
    __syncthreads();
    for (int s = 128; s > 0; s >>= 1) {
        if (tid < s) { r0[tid] += r0[tid + s]; r1[tid] += r1[tid + s]; }
        __syncthreads();
    }
    if (tid == 0) {
        out[b * 2 + 0] = r0[0] + bd[0];
        out[b * 2 + 1] = r1[0] + bd[1];
    }
}

// ---------------------------------------------------------------------------
extern "C" void kernel_launch(void* const* d_in, const int* in_sizes, int n_in,
                              void* d_out, int out_size, void* d_ws, size_t ws_size,
                              hipStream_t stream)
{
    const int*   sentence = (const int*)d_in[0];
    const int*   lens     = (const int*)d_in[1];
    const float* emb      = (const float*)d_in[2];
    const float* Wihf     = (const float*)d_in[3];
    const float* Whhf     = (const float*)d_in[4];
    const float* bf       = (const float*)d_in[5];
    const float* Wihb     = (const float*)d_in[6];
    const float* Whhb     = (const float*)d_in[7];
    const float* bb       = (const float*)d_in[8];
    const float* Wd       = (const float*)d_in[9];
    const float* bd       = (const float*)d_in[10];
    float* out = (float*)d_out;

    _Float16* EGh = (_Float16*)d_ws;                // [4096][2][256] half2 = 8 MB
    float* pws = (float*)(EGh + (size_t)VV * 1024); // [64][2][8][128] fp32 = 512 KB

    eg_gemm<<<dim3(16, 64), 256, 0, stream>>>(emb, Wihf, bf, Wihb, bb, EGh);
    lstm_rec<<<64, 256, 0, stream>>>(sentence, lens, Whhf, Whhb, EGh, pws);
    dense_k<<<64, 256, 0, stream>>>(pws, Wd, bd, out);
}

// Round 8
// 1563.699 us; speedup vs baseline: 2.4773x; 2.4773x over previous
//
#include <hip/hip_runtime.h>
#include <hip/hip_bf16.h>
#include <math.h>

// Problem constants (from reference)
#define BB 64
#define TT 2048
#define VV 4096
#define EE 128
#define H2 128
#define SS 8
#define CC 2

typedef _Float16 h2f __attribute__((ext_vector_type(2)));

__device__ __forceinline__ float sigf(float x) { return 1.f / (1.f + __expf(-x)); }
__device__ __forceinline__ float tanh_fast(float x) { return 1.f - 2.f / (__expf(2.f * x) + 1.f); }

__device__ __forceinline__ float dot2acc(h2f w, h2f h, float acc) {
#if __has_builtin(__builtin_amdgcn_fdot2)
    return __builtin_amdgcn_fdot2(w, h, acc, false);
#else
    return fmaf((float)w.x, (float)h.x, fmaf((float)w.y, (float)h.y, acc));
#endif
}

// Workgroup barrier with LDS-only drain (no vmcnt(0) — global prefetch loads
// stay in flight across steps).
__device__ __forceinline__ void lds_barrier() {
    asm volatile("s_waitcnt lgkmcnt(0)\n\ts_barrier" ::: "memory");
}

// ---------------------------------------------------------------------------
// Kernel 1: EG gate-bias table, packed f16 PAIR layout:
//   EGh[v][d][p] = half2{ gate rA(p), gate rB(p) },  p in [0,256)
//   p<128: rA=p (i_u), rB=128+p (f_u);  p>=128: rA=128+p (g_u), rB=256+p (o_u)
// ---------------------------------------------------------------------------
__global__ __launch_bounds__(256) void eg_gemm(
    const float* __restrict__ emb,
    const float* __restrict__ Wf, const float* __restrict__ bf,
    const float* __restrict__ Wb, const float* __restrict__ bb,
    _Float16* __restrict__ EGh)
{
    __shared__ float As[64][68];
    __shared__ float Bs[64][68];

    const int tid = threadIdx.x;
    const int tx = tid & 15, ty = tid >> 4;
    const int m0 = blockIdx.y * 64;
    const int n0 = blockIdx.x * 64;

    const float* Bsrc;
    const float* bias;
    if (n0 < 512) { Bsrc = Wf + n0 * EE; bias = bf + n0; }
    else          { Bsrc = Wb + (n0 - 512) * EE; bias = bb + (n0 - 512); }

    float acc[4][4] = {};

    for (int kc = 0; kc < 2; ++kc) {
        for (int c = tid; c < 1024; c += 256) {
            int r = c >> 4, q = c & 15;
            float4 av = *(const float4*)(emb + (size_t)(m0 + r) * EE + kc * 64 + q * 4);
            As[q * 4 + 0][r] = av.x; As[q * 4 + 1][r] = av.y;
            As[q * 4 + 2][r] = av.z; As[q * 4 + 3][r] = av.w;
            float4 bv = *(const float4*)(Bsrc + (size_t)r * EE + kc * 64 + q * 4);
            Bs[q * 4 + 0][r] = bv.x; Bs[q * 4 + 1][r] = bv.y;
            Bs[q * 4 + 2][r] = bv.z; Bs[q * 4 + 3][r] = bv.w;
        }
        __syncthreads();
        #pragma unroll 8
        for (int k = 0; k < 64; ++k) {
            float4 a4 = *(const float4*)&As[k][4 * ty];
            float4 b4 = *(const float4*)&Bs[k][4 * tx];
            float a[4] = {a4.x, a4.y, a4.z, a4.w};
            float b[4] = {b4.x, b4.y, b4.z, b4.w};
            #pragma unroll
            for (int i = 0; i < 4; ++i)
                #pragma unroll
                for (int jn = 0; jn < 4; ++jn)
                    acc[i][jn] = fmaf(a[i], b[jn], acc[i][jn]);
        }
        __syncthreads();
    }

    #pragma unroll
    for (int i = 0; i < 4; ++i) {
        int m = m0 + 4 * ty + i;                 // vocab index v
        #pragma unroll
        for (int jn = 0; jn < 4; ++jn) {
            int nn = 4 * tx + jn;
            int n = n0 + nn;                     // combined gate col
            int d = n >> 9;
            int r = n & 511;
            int slot = (r >> 7) & 1;
            int p = (r & 127) + (r >= 256 ? 128 : 0);
            EGh[(((size_t)m * 2 + d) * 256 + p) * 2 + slot] =
                (_Float16)(acc[i][jn] + bias[nn]);
        }
    }
}

// ---------------------------------------------------------------------------
// Kernel 2: fused LSTM recurrence + ragged segment max-pool.
// grid = 128 blocks (b,dir). 256 threads = 4 waves, 1 wave/SIMD (proven R4/R5
// shape — 2-stream/512-thread variants die on the register allocator).
// Wave wg, lane l: unit u = wg*32 + (l>>1).
//   even lane: W_hh rows (i_u,f_u) + cell state; odd: (g_u,o_u).
// R8 changes vs R5: (1) dot uses FOUR independent accumulator chains
// (k-low/k-high per row) to hide v_dot2 ~4-cyc latency — R5 ran 2 chains =
// ~50% dead issue slots in the 128-dot2 loop; (2) amdgpu_waves_per_eu(1,1)
// so the allocator has no occupancy incentive to pin arch VGPRs at 136.
// ---------------------------------------------------------------------------
__global__
__attribute__((amdgpu_flat_work_group_size(256, 256), amdgpu_waves_per_eu(1, 1)))
void lstm_rec(
    const int* __restrict__ sentence, const int* __restrict__ lens,
    const float* __restrict__ Whhf, const float* __restrict__ Whhb,
    const _Float16* __restrict__ EGh, float* __restrict__ pws)
{
    const int bid = blockIdx.x;
    const int b = bid >> 1;
    const int dir = bid & 1;            // 0 = forward, 1 = backward
    const int tid = threadIdx.x;
    const int l = tid & 63;             // lane in wave
    const int wg = tid >> 6;            // wave 0..3
    const int u = wg * 32 + (l >> 1);   // hidden unit this lane pair covers
    const bool evn = (l & 1) == 0;      // even lane: (i,f) + cell state
    const int L = lens[b];
    const int* __restrict__ srow = sentence + (size_t)b * TT;

    const int r0 = evn ? u : (256 + u);
    const int r1 = r0 + 128;
    const float* __restrict__ Wh = (dir == 0 ? Whhf : Whhb);

    // --- W_hh rows -> packed f16 pairs: 128 regs ---
    h2f w0[64], w1[64];
    #pragma unroll
    for (int k4 = 0; k4 < 32; ++k4) {
        float4 a = *(const float4*)(Wh + (size_t)r0 * H2 + 4 * k4);
        w0[2 * k4 + 0].x = (_Float16)a.x; w0[2 * k4 + 0].y = (_Float16)a.y;
        w0[2 * k4 + 1].x = (_Float16)a.z; w0[2 * k4 + 1].y = (_Float16)a.w;
        float4 bq = *(const float4*)(Wh + (size_t)r1 * H2 + 4 * k4);
        w1[2 * k4 + 0].x = (_Float16)bq.x; w1[2 * k4 + 0].y = (_Float16)bq.y;
        w1[2 * k4 + 1].x = (_Float16)bq.z; w1[2 * k4 + 1].y = (_Float16)bq.w;
    }

    __shared__ int hpk[2][64];          // double-buffered packed f16 h pairs
    if (tid < 64) hpk[0][tid] = 0;

    // per-lane EG pair element (as packed dword); dword index for token v:
    // v*512 (egp already offset by dir*256+p)
    const int p = evn ? u : (128 + u);
    const unsigned* __restrict__ egp = (const unsigned*)EGh + dir * 256 + p;

    // hoisted pooling output row base
    float* __restrict__ prow = pws + ((size_t)b * 2 + dir) * SS * H2 + u;

    float c = 0.f;
    float pm = -INFINITY;

    const int wseg = (L + SS - 1) >> 3;
    const bool haspad = (SS * wseg > L);
    const int padlo = L / wseg;
    int cur_seg = dir ? (SS - 1) : 0;
    int nb = dir ? (SS - 1) * wseg : wseg;

    // --- prefetch FIFO depth 3 ---
    int i0 = dir ? (L - 1) : 0;
    int i1 = dir ? max(0, L - 2) : min(TT - 1, 1);
    int i2 = dir ? max(0, L - 3) : min(TT - 1, 2);
    int i3 = dir ? max(0, L - 4) : min(TT - 1, 3);
    unsigned xf0 = egp[(size_t)srow[i0] * 512];
    unsigned xf1 = egp[(size_t)srow[i1] * 512];
    unsigned xf2 = egp[(size_t)srow[i2] * 512];
    int tok3 = srow[i3];

    __syncthreads();                    // hpk init visible (one-time drain)

    for (int t = 0; t < L; ++t) {
        const int buf = t & 1;
        // ---- h for this step (written before the previous barrier) ----
        int hp = hpk[buf][l];

        // ---- issue EG gather for step t+3 (lives across 3 barriers) ----
        unsigned pf = egp[(size_t)tok3 * 512];
        int i4 = dir ? max(0, L - 5 - t) : min(TT - 1, t + 4);
        tok3 = srow[i4];

        // ---- dot: 64 readlane + 128 v_dot2, FOUR independent acc chains ----
        float a0lo = 0.f, a0hi = 0.f, a1lo = 0.f, a1hi = 0.f;
        #pragma unroll
        for (int k = 0; k < 32; ++k) {
            int hkl = __builtin_amdgcn_readlane(hp, k);
            int hkh = __builtin_amdgcn_readlane(hp, k + 32);
            h2f hvl = __builtin_bit_cast(h2f, hkl);
            h2f hvh = __builtin_bit_cast(h2f, hkh);
            a0lo = dot2acc(w0[k], hvl, a0lo);
            a1lo = dot2acc(w1[k], hvl, a1lo);
            a0hi = dot2acc(w0[k + 32], hvh, a0hi);
            a1hi = dot2acc(w1[k + 32], hvh, a1hi);
        }
        h2f xv = __builtin_bit_cast(h2f, xf0);
        float g0 = (a0lo + a0hi) + (float)xv.x;  // even: i-preact ; odd: g-preact
        float g1 = (a1lo + a1hi) + (float)xv.y;  // even: f-preact ; odd: o-preact

        // ---- own activations ----
        float s_own = sigf(g1);                              // sf | so
        float t_own = evn ? sigf(g0) : tanh_fast(g0);        // si | tg

        // ---- pair exchange (intra-wave, lockstep) ----
        float t_x = __shfl_xor(t_own, 1, 64);
        float s_x = __shfl_xor(s_own, 1, 64);

        // even lane: c = sf*c + si*tg ; h = so*tanh(c). (odd computes garbage)
        c = s_own * c + t_own * t_x;
        float hn = s_x * tanh_fast(c);

        // ---- pooling bookkeeping (uniform branch) ----
        const int tt = dir ? (L - 1 - t) : t;
        bool bnd = dir ? (tt < nb) : (tt >= nb);
        if (bnd) {
            if (evn) {
                float v = pm;
                if (haspad && cur_seg >= padlo) v = fmaxf(v, 0.f);
                prow[(size_t)cur_seg * H2] = v;
            }
            pm = -INFINITY;
            cur_seg += dir ? -1 : 1;
            nb += dir ? -wseg : wseg;
        }
        pm = fmaxf(pm, hn);

        // ---- publish h (f16) into the other buffer; LDS-only barrier ----
        if (evn) ((_Float16*)hpk[buf ^ 1])[u] = (_Float16)hn;
        lds_barrier();

        // rotate prefetch FIFO
        xf0 = xf1; xf1 = xf2; xf2 = pf;
    }

    if (evn) {
        float v = pm;
        if (haspad && cur_seg >= padlo) v = fmaxf(v, 0.f);
        prow[(size_t)cur_seg * H2] = v;
    }
}

// ---------------------------------------------------------------------------
// Kernel 3: out[b,c] = b_dense[c] + sum_k flat[b,k] * W_dense[c,k]
// ---------------------------------------------------------------------------
__global__ __launch_bounds__(256) void dense_k(
    const float* __restrict__ pws, const float* __restrict__ Wd,
    const float* __restrict__ bd, float* __restrict__ out)
{
    const int b = blockIdx.x;
    const int tid = threadIdx.x;
    float a0 = 0.f, a1 = 0.f;
    for (int k = tid; k < 2048; k += 256) {
        int h = k >> 3, s = k & 7;
        int dir = h >> 7, j = h & 127;
        float v = pws[(((size_t)b * 2 + dir) * SS + s) * H2 + j];
        a0 = fmaf(v, Wd[k], a0);
        a1 = fmaf(v, Wd[2048 + k], a1);
    }
    __shared__ float r0[256], r1[256];
    r0[tid] = a0; r1[tid] = a1;
    __syncthreads();
    for (int s = 128; s > 0; s >>= 1) {
        if (tid < s) { r0[tid] += r0[tid + s]; r1[tid] += r1[tid + s]; }
        __syncthreads();
    }
    if (tid == 0) {
        out[b * 2 + 0] = r0[0] + bd[0];
        out[b * 2 + 1] = r1[0] + bd[1];
    }
}

// ---------------------------------------------------------------------------
extern "C" void kernel_launch(void* const* d_in, const int* in_sizes, int n_in,
                              void* d_out, int out_size, void* d_ws, size_t ws_size,
                              hipStream_t stream)
{
    const int*   sentence = (const int*)d_in[0];
    const int*   lens     = (const int*)d_in[1];
    const float* emb      = (const float*)d_in[2];
    const float* Wihf     = (const float*)d_in[3];
    const float* Whhf     = (const float*)d_in[4];
    const float* bf       = (const float*)d_in[5];
    const float* Wihb     = (const float*)d_in[6];
    const float* Whhb     = (const float*)d_in[7];
    const float* bb       = (const float*)d_in[8];
    const float* Wd       = (const float*)d_in[9];
    const float* bd       = (const float*)d_in[10];
    float* out = (float*)d_out;

    _Float16* EGh = (_Float16*)d_ws;                // [4096][2][256] half2 = 8 MB
    float* pws = (float*)(EGh + (size_t)VV * 1024); // [64][2][8][128] fp32 = 512 KB

    eg_gemm<<<dim3(16, 64), 256, 0, stream>>>(emb, Wihf, bf, Wihb, bb, EGh);
    lstm_rec<<<128, 256, 0, stream>>>(sentence, lens, Whhf, Whhb, EGh, pws);
    dense_k<<<64, 256, 0, stream>>>(pws, Wd, bd, out);
}